// Round 6
// baseline (3606.588 us; speedup 1.0000x reference)
//
#include <hip/hip_runtime.h>
#include <hip/hip_cooperative_groups.h>
#include <math.h>

namespace cg = cooperative_groups;

#define BB 8
#define CC 256
#define NN 16384
#define NBVEC 16
#define NBLK 512     // 2 blocks/CU with __launch_bounds__(256,2): PROVEN to launch (round 2)
#define COLS 256     // phase-A columns per block (one per thread)

// ---- workspace (bytes) ----
// wsum   double[16][8][256] @ 0        : 262144  (atomicAdd, zeroed in preamble)
// sumSim double[16][8]      @ 262144   : 1024    (atomicAdd, zeroed in preamble)
// simbuf double[8][16384]   @ 263168   : 1048576 (f64 sim, rewritten each iter)
// blkval double[16][512]    @ 1311744  : 65536
// blkidx int   [16][512]    @ 1377280  : 32768
// rv     float [8][256]     @ 1410048  : 8192

__global__ void __launch_bounds__(256, 2)
neighsim_v6(const float* __restrict__ x, float* __restrict__ out,
            double* __restrict__ wsum, double* __restrict__ sumSim,
            double* __restrict__ simbuf,
            double* __restrict__ blkval, int* __restrict__ blkidx,
            float* __restrict__ rv)
{
    cg::grid_group grid = cg::this_grid();
    const int t     = threadIdx.x;
    const int blk   = blockIdx.x;
    const int b     = blk & 7;          // batch (blk%8: one batch per XCD slice)
    const int chunk = blk >> 3;         // 0..63
    const int n0    = chunk * COLS;
    const int n     = n0 + t;           // this thread's column (phase A)

    __shared__ float  s_rv[CC];
    __shared__ double s_val[256];
    __shared__ int    s_idx[256];

    float* out_repr   = out;                                      // [NB][B][C]
    float* out_sims   = out + NBVEC*BB*CC;                        // [NB][B][N]
    float* out_selpos = out + NBVEC*BB*CC + (size_t)NBVEC*BB*NN;  // [B][N]

    const float* xb = x + (size_t)b*CC*NN;

    // ---------------- preamble ----------------
    {
        int g = blk*256 + t;                       // [0, 131072) == BB*NN exactly
        if (g < NBVEC*BB*CC) wsum[g] = 0.0;
        if (g < NBVEC*BB)    sumSim[g] = 0.0;
        // selpos init with the deterministic i==0 center pick baked in
        out_selpos[g] = ((g & (NN-1)) == NN/2) ? 1.0f : 0.0f;
    }
    if (blk < BB)            // rv for i==0 (prior input is dead code in the ref)
        rv[blk*CC + t] = x[(size_t)blk*CC*NN + (size_t)t*NN + NN/2];
    __threadfence();
    grid.sync();

    double score = 0.0;      // this thread's score[n]

    for (int i = 0; i < NBVEC; ++i) {
        // ================= segment 1 =================
        // repr(i-1) by blocks 0..7 — atomics for iter i-1 completed before the
        // grid.sync that ended the previous loop body.
        if (i >= 1 && blk < BB) {
            double ss = sumSim[(i-1)*BB + blk];
            out_repr[(size_t)(i-1)*BB*CC + blk*CC + t] =
                (float)(wsum[(size_t)((i-1)*BB + blk)*CC + t] / ss);
        }

        // ---- phaseA(i): full 256-channel f64 loop (round-1/2-proven order)
        s_rv[t] = rv[b*CC + t];
        __syncthreads();
        double acc = 0.0;
        #pragma unroll 8
        for (int c = 0; c < CC; ++c) {             // coalesced b32, lane = column
            double diff = (double)xb[(size_t)c*NN + n] - (double)s_rv[c];
            acc = fma(diff, diff, acc);
        }
        double d   = sqrt(acc + 1e-12);
        double sim = exp(-(d / 20.0));
        simbuf[(size_t)b*NN + n] = sim;
        out_sims[(size_t)i*BB*NN + (size_t)b*NN + n] = (float)sim;
        score = (i == 0) ? (1.0 - sim) : (1.0 - sim) * score;

        // block partial of sum(sim) -> one f64 atomic per block
        s_val[t] = sim;
        __syncthreads();
        for (int s = 128; s > 0; s >>= 1) {
            if (t < s) s_val[t] += s_val[t + s];
            __syncthreads();
        }
        if (t == 0) atomicAdd(&sumSim[i*BB + b], s_val[0]);
        __syncthreads();

        // block argmax (first occurrence: lower n wins ties)
        if (i < NBVEC-1) {
            s_val[t] = score; s_idx[t] = n;
            __syncthreads();
            for (int s = 128; s > 0; s >>= 1) {
                if (t < s) {
                    double v2 = s_val[t+s]; int i2 = s_idx[t+s];
                    if (v2 > s_val[t] || (v2 == s_val[t] && i2 < s_idx[t])) {
                        s_val[t] = v2; s_idx[t] = i2;
                    }
                }
                __syncthreads();
            }
            if (t == 0) { blkval[i*NBLK + blk] = s_val[0];
                          blkidx[i*NBLK + blk] = s_idx[0]; }
        }
        __threadfence();
        grid.sync();

        // ================= segment 2 =================
        // selection(i) -> rv(i+1): blocks 0..7 only (round-2-proven pattern)
        if (i < NBVEC-1 && blk < BB) {
            if (t < 64) { s_val[t] = blkval[i*NBLK + blk + 8*t];
                          s_idx[t] = blkidx[i*NBLK + blk + 8*t]; }
            else        { s_val[t] = -1.0e300; s_idx[t] = 0x7fffffff; }
            __syncthreads();
            for (int s = 128; s > 0; s >>= 1) {
                if (t < s) {
                    double v2 = s_val[t+s]; int i2 = s_idx[t+s];
                    if (v2 > s_val[t] || (v2 == s_val[t] && i2 < s_idx[t])) {
                        s_val[t] = v2; s_idx[t] = i2;
                    }
                }
                __syncthreads();
            }
            const int sel = s_idx[0];
            if (t == 0) out_selpos[blk*NN + sel] += 1.0f;
            rv[blk*CC + t] = x[(size_t)blk*CC*NN + (size_t)t*NN + sel];
        }

        // ---- phase2(i): block owns channels c0..c0+3; f64 sim weights
        {
            const int c0 = chunk * 4;
            const float4*  xv0 = (const float4*)(xb + (size_t)(c0  )*NN);
            const float4*  xv1 = (const float4*)(xb + (size_t)(c0+1)*NN);
            const float4*  xv2 = (const float4*)(xb + (size_t)(c0+2)*NN);
            const float4*  xv3 = (const float4*)(xb + (size_t)(c0+3)*NN);
            const double2* sd  = (const double2*)(simbuf + (size_t)b*NN);
            double w0 = 0.0, w1 = 0.0, w2 = 0.0, w3 = 0.0;
            #pragma unroll 2
            for (int k = 0; k < 16; ++k) {
                int q = t + k*256;                 // float4-quad index, 0..4095
                double2 s0 = sd[2*q];
                double2 s1 = sd[2*q + 1];
                float4  a4 = xv0[q];
                float4  b4 = xv1[q];
                float4  c4 = xv2[q];
                float4  e4 = xv3[q];
                w0 = fma(s0.x, (double)a4.x, w0); w0 = fma(s0.y, (double)a4.y, w0);
                w0 = fma(s1.x, (double)a4.z, w0); w0 = fma(s1.y, (double)a4.w, w0);
                w1 = fma(s0.x, (double)b4.x, w1); w1 = fma(s0.y, (double)b4.y, w1);
                w1 = fma(s1.x, (double)b4.z, w1); w1 = fma(s1.y, (double)b4.w, w1);
                w2 = fma(s0.x, (double)c4.x, w2); w2 = fma(s0.y, (double)c4.y, w2);
                w2 = fma(s1.x, (double)c4.z, w2); w2 = fma(s1.y, (double)c4.w, w2);
                w3 = fma(s0.x, (double)e4.x, w3); w3 = fma(s0.y, (double)e4.y, w3);
                w3 = fma(s1.x, (double)e4.z, w3); w3 = fma(s1.y, (double)e4.w, w3);
            }
            __syncthreads();                       // selection is done with s_val
            double wreg[4] = { w0, w1, w2, w3 };
            #pragma unroll
            for (int cc = 0; cc < 4; ++cc) {
                s_val[t] = wreg[cc];
                __syncthreads();
                for (int s = 128; s > 0; s >>= 1) {
                    if (t < s) s_val[t] += s_val[t + s];
                    __syncthreads();
                }
                if (t == 0)
                    atomicAdd(&wsum[(size_t)(i*BB + b)*CC + c0 + cc], s_val[0]);
                __syncthreads();
            }
        }
        __threadfence();
        grid.sync();
    }

    // epilogue: repr(15)
    if (blk < BB) {
        double ss = sumSim[15*BB + blk];
        out_repr[(size_t)15*BB*CC + blk*CC + t] =
            (float)(wsum[(size_t)(15*BB + blk)*CC + t] / ss);
    }
}

extern "C" void kernel_launch(void* const* d_in, const int* in_sizes, int n_in,
                              void* d_out, int out_size, void* d_ws, size_t ws_size,
                              hipStream_t stream)
{
    const float* x = (const float*)d_in[0];
    // d_in[1] (prior) provably unused; d_in[2] (nbVec) fixed at 16.
    float* out = (float*)d_out;

    char* ws = (char*)d_ws;
    double* wsum   = (double*)(ws);
    double* sumSim = (double*)(ws + 262144);
    double* simbuf = (double*)(ws + 263168);
    double* blkval = (double*)(ws + 1311744);
    int*    blkidx = (int*)   (ws + 1377280);
    float*  rv     = (float*) (ws + 1410048);

    void* args[] = { (void*)&x, (void*)&out, (void*)&wsum, (void*)&sumSim,
                     (void*)&simbuf, (void*)&blkval, (void*)&blkidx, (void*)&rv };
    hipLaunchCooperativeKernel((void*)neighsim_v6,
                               dim3(NBLK), dim3(256), args, 0, stream);
}